// Round 7
// baseline (471.251 us; speedup 1.0000x reference)
//
#include <hip/hip_runtime.h>
#include <hip/hip_bf16.h>

// ---------------- problem constants ----------------
#define BATCH   16
#define C_INF   4
#define H_IN    128
#define W_IN    128
#define HID     50
#define F_OUT   18
#define HO      120
#define WO      120
#define OH      122
#define OW      122
#define NPOS    (BATCH * HO * WO)       // 230400 = 1800 * 128
#define MBLK    128                     // positions per unit
#define NBLKS   (NPOS / MBLK)           // 1800 units
#define NB      512                     // persistent grid (2 blocks/CU guaranteed)

// frag-packed weight blob sizes (bf16 shorts)
#define NB1     (11*4*2*64*8)           // 45056
#define NB2     (2*4*2*64*8)            // 8192
#define NB3     (2*2*2*64*8)            // 4096
#define NWF     (NB1 + NB2 + NB3)
#define NXP     (BATCH*C_INF*H_IN*W_IN) // 1048576 packed x elements
#define WOFF    (NPOS * F_OUT)          // out3 floats
#define NOUT    (BATCH * 2 * OH * OW)   // 476288

typedef float  v4f    __attribute__((ext_vector_type(4)));
typedef short  short8 __attribute__((ext_vector_type(8)));
typedef __bf16 v8bf   __attribute__((ext_vector_type(8)));
typedef int    v4i    __attribute__((ext_vector_type(4)));
typedef uint   u32x4  __attribute__((ext_vector_type(4)));
typedef u32x4  u32x4_a4 __attribute__((aligned(4)));   // 16B load, 4B-aligned ok

__device__ inline short f2bf_hi(float x) {
    __hip_bfloat16 h = __float2bfloat16(x);      // RNE
    return __builtin_bit_cast(short, h);
}
__device__ inline float bf2f(short s) {
    __hip_bfloat16 h = __builtin_bit_cast(__hip_bfloat16, s);
    return __bfloat162float(h);
}
__device__ inline uint hipair(uint a, uint b) { return __builtin_amdgcn_perm(b, a, 0x07060302u); }
__device__ inline uint lopair(uint a, uint b) { return __builtin_amdgcn_perm(b, a, 0x05040100u); }

// slot -> k bijection for layer 1 (contiguous kj in the low 9 k-steps)
__device__ inline int slot_to_k1(int s, int qb, int e) {
    if (s < 9) {
        int pair = s*4 + qb;            // (c,ki) in [0,36)
        int c = pair/9, ki = pair - c*9;
        return c*81 + ki*9 + e;         // kj = e in [0,8)
    }
    int r = (s-9)*32 + qb*8 + e;        // remainder: kj = 8
    if (r >= 36) return -1;
    int c = r/9, ki = r - c*9;
    return c*81 + ki*9 + 8;
}

// device-scope grid barrier over NB co-resident blocks (flags array per barrier)
__device__ inline void gbar(uint* flags, uint tag) {
    __threadfence();                 // release this thread's prior writes
    __syncthreads();                 // whole block done + fenced
    if (threadIdx.x == 0)
        __hip_atomic_store(&flags[blockIdx.x], tag, __ATOMIC_RELEASE, __HIP_MEMORY_SCOPE_AGENT);
    for (int f = (int)threadIdx.x; f < NB; f += 256) {
        while (__hip_atomic_load(&flags[f], __ATOMIC_ACQUIRE, __HIP_MEMORY_SCOPE_AGENT) != tag)
            __builtin_amdgcn_s_sleep(2);
    }
    __syncthreads();
    __threadfence();                 // acquire: invalidate stale cached data
}

// ---------------- single fused persistent kernel ----------------
__global__ __launch_bounds__(256, 2)
void fused_kernel(const float* __restrict__ x,
                  const float* __restrict__ W1, const float* __restrict__ b1,
                  const float* __restrict__ W2, const float* __restrict__ b2,
                  const float* __restrict__ W3, const float* __restrict__ b3,
                  float* __restrict__ out3, short* __restrict__ wf,
                  uint* __restrict__ xp, uint* flags1, uint* flags2,
                  float* __restrict__ out)
{
    __shared__ short h_hi[128 * 72];   // 18432 B; also reused as fp32 transpose buf

    const int tid  = threadIdx.x;
    const int bid  = blockIdx.x;

    // reset barrier state (makes stale/poisoned flags benign; ordered before
    // this block's flags1 release inside gbar)
    if (tid == 0) {
        __hip_atomic_store(&flags1[bid], 0u, __ATOMIC_RELAXED, __HIP_MEMORY_SCOPE_AGENT);
        __hip_atomic_store(&flags2[bid], 0u, __ATOMIC_RELAXED, __HIP_MEMORY_SCOPE_AGENT);
    }

    // ================= phase 0: pack x (hi,lo) + weight b-frag images =================
    for (int gi = bid*256 + tid; gi < NXP + NWF; gi += NB*256) {
        if (gi < NXP) {
            float v = x[gi];
            short hi = f2bf_hi(v);
            short lo = f2bf_hi(v - bf2f(hi));
            xp[gi] = ((uint)(ushort)hi << 16) | (uint)(ushort)lo;
        } else {
            int i = gi - NXP;
            float val; int p;
            if (i < NB1) {
                int t = i;
                int e = t & 7, lane = (t >> 3) & 63; p = (t >> 9) & 1;
                int rest = t >> 10;                  // s*4 + u
                int u = rest & 3, s = rest >> 2;
                int k = slot_to_k1(s, lane >> 4, e);
                int n = u*16 + (lane & 15);
                val = (k >= 0 && n < HID) ? W1[k*HID + n] : 0.f;
            } else if (i < NB1 + NB2) {
                int t = i - NB1;
                int e = t & 7, lane = (t >> 3) & 63; p = (t >> 9) & 1;
                int rest = t >> 10;
                int u = rest & 3, s = rest >> 2;
                int k = s*32 + ((lane >> 4) << 3) + e;   // linear (LDS h layout)
                int n = u*16 + (lane & 15);
                val = (k < HID && n < HID) ? W2[k*HID + n] : 0.f;
            } else {
                int t = i - NB1 - NB2;
                int e = t & 7, lane = (t >> 3) & 63; p = (t >> 9) & 1;
                int rest = t >> 10;
                int u = rest & 1, s = rest >> 1;
                int k = s*32 + ((lane >> 4) << 3) + e;
                int n = u*16 + (lane & 15);
                val = (k < HID && n < F_OUT) ? W3[k*F_OUT + n] : 0.f;
            }
            short hi = f2bf_hi(val);
            wf[i] = (p == 0) ? hi : f2bf_hi(val - bf2f(hi));
        }
    }

    gbar(flags1, 1u);

    // ================= phase 1: MFMA MLP units =================
    const int lane = tid & 63;
    const int w    = tid >> 6;
    const int wm   = w >> 1, wn = w & 1;
    const int q    = lane >> 4, col = lane & 15;

    const v4i* B1 = (const v4i*)wf;
    const v4i* B2 = (const v4i*)(wf + NB1);
    const v4i* B3 = (const v4i*)(wf + NB1 + NB2);

    for (int unit = bid; unit < NBLKS; unit += NB) {
        const int mbase = unit * MBLK;

        int xbase[4];
        #pragma unroll
        for (int t = 0; t < 4; ++t) {
            int pos = mbase + wm*64 + t*16 + col;
            int b   = pos / (HO*WO); int rem = pos - b*(HO*WO);
            int y   = rem / WO;      int xc  = rem - y*WO;
            xbase[t] = b*(C_INF*H_IN*W_IN) + y*W_IN + xc;
        }

        // ---------------- layer 1: K=324 (11 k-steps), N=64 ----------------
        v4f acc[4][2];
        #pragma unroll
        for (int t = 0; t < 4; ++t)
            #pragma unroll
            for (int u = 0; u < 2; ++u)
                acc[t][u] = (v4f){0.f, 0.f, 0.f, 0.f};

        #pragma unroll 3
        for (int s = 0; s < 9; ++s) {
            const int pair = s*4 + q;
            const int c = pair/9, ki = pair - c*9;
            const int off = c*(H_IN*W_IN) + ki*W_IN;

            v4i bhv[2], blv[2];
            #pragma unroll
            for (int uu = 0; uu < 2; ++uu) {
                int u  = 2*wn + uu;
                int fb = ((s*4 + u)*2)*64 + lane;
                bhv[uu] = B1[fb];
                blv[uu] = B1[fb + 64];
            }

            u32x4 wa[4], wb[4];
            #pragma unroll
            for (int t = 0; t < 4; ++t) {
                const uint* p = &xp[xbase[t] + off];
                wa[t] = *(const u32x4_a4*)(p);       // kj 0..3
                wb[t] = *(const u32x4_a4*)(p + 4);   // kj 4..7
            }
            short8 ah[4], al[4];
            #pragma unroll
            for (int t = 0; t < 4; ++t) {
                u32x4 hh, ll;
                hh.x = hipair(wa[t].x, wa[t].y); hh.y = hipair(wa[t].z, wa[t].w);
                hh.z = hipair(wb[t].x, wb[t].y); hh.w = hipair(wb[t].z, wb[t].w);
                ll.x = lopair(wa[t].x, wa[t].y); ll.y = lopair(wa[t].z, wa[t].w);
                ll.z = lopair(wb[t].x, wb[t].y); ll.w = lopair(wb[t].z, wb[t].w);
                ah[t] = __builtin_bit_cast(short8, hh);
                al[t] = __builtin_bit_cast(short8, ll);
            }
            #pragma unroll
            for (int uu = 0; uu < 2; ++uu) {
                v8bf bh = __builtin_bit_cast(v8bf, bhv[uu]);
                v8bf bl = __builtin_bit_cast(v8bf, blv[uu]);
                #pragma unroll
                for (int t = 0; t < 4; ++t) {
                    v8bf a_h = __builtin_bit_cast(v8bf, ah[t]);
                    v8bf a_l = __builtin_bit_cast(v8bf, al[t]);
                    acc[t][uu] = __builtin_amdgcn_mfma_f32_16x16x32_bf16(a_h, bh, acc[t][uu], 0, 0, 0);
                    acc[t][uu] = __builtin_amdgcn_mfma_f32_16x16x32_bf16(a_l, bh, acc[t][uu], 0, 0, 0);
                    acc[t][uu] = __builtin_amdgcn_mfma_f32_16x16x32_bf16(a_h, bl, acc[t][uu], 0, 0, 0);
                }
            }
        }
        // 2 remainder steps (kj = 8)
        #pragma unroll
        for (int sr = 0; sr < 2; ++sr) {
            const int s = 9 + sr;
            short8 ah[4], al[4];
            #pragma unroll
            for (int e = 0; e < 8; ++e) {
                int r = sr*32 + q*8 + e;
                bool valid = (r < 36);
                int c = valid ? r/9 : 0;
                int ki = r - c*9;
                int off = c*(H_IN*W_IN) + ki*W_IN + 8;
                #pragma unroll
                for (int t = 0; t < 4; ++t) {
                    uint wv = valid ? xp[xbase[t] + off] : 0u;
                    ah[t][e] = (short)(wv >> 16);
                    al[t][e] = (short)(wv & 0xffffu);
                }
            }
            #pragma unroll
            for (int uu = 0; uu < 2; ++uu) {
                int u  = 2*wn + uu;
                int fb = ((s*4 + u)*2)*64 + lane;
                v8bf bh = __builtin_bit_cast(v8bf, B1[fb]);
                v8bf bl = __builtin_bit_cast(v8bf, B1[fb + 64]);
                #pragma unroll
                for (int t = 0; t < 4; ++t) {
                    v8bf a_h = __builtin_bit_cast(v8bf, ah[t]);
                    v8bf a_l = __builtin_bit_cast(v8bf, al[t]);
                    acc[t][uu] = __builtin_amdgcn_mfma_f32_16x16x32_bf16(a_h, bh, acc[t][uu], 0, 0, 0);
                    acc[t][uu] = __builtin_amdgcn_mfma_f32_16x16x32_bf16(a_l, bh, acc[t][uu], 0, 0, 0);
                    acc[t][uu] = __builtin_amdgcn_mfma_f32_16x16x32_bf16(a_h, bl, acc[t][uu], 0, 0, 0);
                }
            }
        }

        // epilogue L1: + b1, relu, bf16-hi into LDS (C/D: row = q*4+r, col = lane&15)
        #pragma unroll
        for (int uu = 0; uu < 2; ++uu) {
            int j = (2*wn + uu)*16 + col;
            float bias = (j < HID) ? b1[j] : 0.f;
            #pragma unroll
            for (int t = 0; t < 4; ++t) {
                #pragma unroll
                for (int r = 0; r < 4; ++r) {
                    float v = fmaxf(acc[t][uu][r] + bias, 0.f);
                    int m = wm*64 + t*16 + q*4 + r;
                    h_hi[m*72 + j] = f2bf_hi(v);
                }
            }
        }
        __syncthreads();

        // ---------------- layer 2: K=50 (2 k-steps), N=64, a=hi only ----------------
        v4f acc2[4][2];
        #pragma unroll
        for (int t = 0; t < 4; ++t)
            #pragma unroll
            for (int u = 0; u < 2; ++u)
                acc2[t][u] = (v4f){0.f, 0.f, 0.f, 0.f};

        #pragma unroll
        for (int s = 0; s < 2; ++s) {
            short8 ah2[4];
            #pragma unroll
            for (int t = 0; t < 4; ++t) {
                int m = wm*64 + t*16 + col;
                ah2[t] = *(const short8*)&h_hi[m*72 + s*32 + q*8];
            }
            #pragma unroll
            for (int uu = 0; uu < 2; ++uu) {
                int u  = 2*wn + uu;
                int fb = ((s*4 + u)*2)*64 + lane;
                v8bf bh = __builtin_bit_cast(v8bf, B2[fb]);
                v8bf bl = __builtin_bit_cast(v8bf, B2[fb + 64]);
                #pragma unroll
                for (int t = 0; t < 4; ++t) {
                    v8bf a_h = __builtin_bit_cast(v8bf, ah2[t]);
                    acc2[t][uu] = __builtin_amdgcn_mfma_f32_16x16x32_bf16(a_h, bh, acc2[t][uu], 0, 0, 0);
                    acc2[t][uu] = __builtin_amdgcn_mfma_f32_16x16x32_bf16(a_h, bl, acc2[t][uu], 0, 0, 0);
                }
            }
        }
        __syncthreads();   // all h1 reads complete before overwrite

        #pragma unroll
        for (int uu = 0; uu < 2; ++uu) {
            int j = (2*wn + uu)*16 + col;
            float bias = (j < HID) ? b2[j] : 0.f;
            #pragma unroll
            for (int t = 0; t < 4; ++t) {
                #pragma unroll
                for (int r = 0; r < 4; ++r) {
                    float v = fmaxf(acc2[t][uu][r] + bias, 0.f);
                    int m = wm*64 + t*16 + q*4 + r;
                    h_hi[m*72 + j] = f2bf_hi(v);
                }
            }
        }
        __syncthreads();

        // ---------------- layer 3: K=50 (2 k-steps), N=18 (pad 32), a=hi only ----------------
        v4f acc3[4];
        #pragma unroll
        for (int t = 0; t < 4; ++t) acc3[t] = (v4f){0.f, 0.f, 0.f, 0.f};

        #pragma unroll
        for (int s = 0; s < 2; ++s) {
            short8 ah3[4];
            #pragma unroll
            for (int t = 0; t < 4; ++t) {
                int m = wm*64 + t*16 + col;
                ah3[t] = *(const short8*)&h_hi[m*72 + s*32 + q*8];
            }
            int fb = ((s*2 + wn)*2)*64 + lane;
            v8bf bh = __builtin_bit_cast(v8bf, B3[fb]);
            v8bf bl = __builtin_bit_cast(v8bf, B3[fb + 64]);
            #pragma unroll
            for (int t = 0; t < 4; ++t) {
                v8bf a_h = __builtin_bit_cast(v8bf, ah3[t]);
                acc3[t] = __builtin_amdgcn_mfma_f32_16x16x32_bf16(a_h, bh, acc3[t], 0, 0, 0);
                acc3[t] = __builtin_amdgcn_mfma_f32_16x16x32_bf16(a_h, bl, acc3[t], 0, 0, 0);
            }
        }
        __syncthreads();   // all h reads done; reuse h_hi as fp32 transpose buffer

        // epilogue: + b3, transpose through LDS (stride 129 floats), coalesced planar stores
        float* ot = (float*)h_hi;      // 18*129*4 = 9288 B <= 18432 B
        {
            int j = wn*16 + col;
            if (j < F_OUT) {
                float bias = b3[j];
                #pragma unroll
                for (int t = 0; t < 4; ++t) {
                    #pragma unroll
                    for (int r = 0; r < 4; ++r) {
                        int m = wm*64 + t*16 + q*4 + r;
                        ot[j*129 + m] = acc3[t][r] + bias;
                    }
                }
            }
        }
        __syncthreads();
        for (int i = tid; i < F_OUT * 128; i += 256) {
            int j2 = i >> 7, m2 = i & 127;
            out3[j2*NPOS + mbase + m2] = ot[j2*129 + m2];
        }
        __syncthreads();   // ot fully read before next unit overwrites h_hi
    }

    gbar(flags2, 1u);

    // ================= phase 2: fold (overlap-add) + divide =================
    for (int idx = bid*256 + tid; idx < NOUT; idx += NB*256) {
        int t = idx;
        const int ox = t % OW; t /= OW;
        const int oy = t % OH; t /= OH;
        const int c  = t & 1;  t >>= 1;
        const int b  = t;

        const int ylo = max(0, oy - 2), yhi = min(HO - 1, oy);
        const int xlo = max(0, ox - 2), xhi = min(WO - 1, ox);

        float s = 0.f;
        for (int y = ylo; y <= yhi; ++y) {
            const int ki = oy - y;
            for (int xx = xlo; xx <= xhi; ++xx) {
                const int kj = ox - xx;
                const int o  = (c*3 + ki)*3 + kj;
                s += out3[o*NPOS + (b*HO + y)*WO + xx];
            }
        }
        const float div = (float)((yhi - ylo + 1) * (xhi - xlo + 1));
        out[idx] = s / div;
    }
}

// ---------------- launch: ONE graph node ----------------
extern "C" void kernel_launch(void* const* d_in, const int* in_sizes, int n_in,
                              void* d_out, int out_size, void* d_ws, size_t ws_size,
                              hipStream_t stream)
{
    const float* x  = (const float*)d_in[0];
    const float* W1 = (const float*)d_in[1];
    const float* b1 = (const float*)d_in[2];
    const float* W2 = (const float*)d_in[3];
    const float* b2 = (const float*)d_in[4];
    const float* W3 = (const float*)d_in[5];
    const float* b3 = (const float*)d_in[6];

    float* out3   = (float*)d_ws;                 // 16.59 MB
    short* wf     = (short*)(out3 + WOFF);        // 112 KB (16-B aligned)
    uint*  xp     = (uint*)(wf + NWF);            // 4 MB
    uint*  flags1 = xp + NXP;                     // 2 KB
    uint*  flags2 = flags1 + NB;                  // 2 KB

    fused_kernel<<<NB, 256, 0, stream>>>(x, W1, b1, W2, b2, W3, b3,
                                         out3, wf, xp, flags1, flags2,
                                         (float*)d_out);
}

// Round 8
// 121.294 us; speedup vs baseline: 3.8852x; 3.8852x over previous
//
#include <hip/hip_runtime.h>
#include <hip/hip_bf16.h>

// ---------------- problem constants ----------------
#define BATCH   16
#define C_INF   4
#define H_IN    128
#define W_IN    128
#define HID     50
#define F_OUT   18
#define HO      120
#define WO      120
#define OH      122
#define OW      122
#define NPOS    (BATCH * HO * WO)       // 230400 = 1800 * 128
#define MBLK    128                     // positions per block
#define NBLKS   (NPOS / MBLK)           // 1800

// frag-packed weight blob sizes (bf16 shorts)
#define NB1     (11*4*2*64*8)           // 45056
#define NB2     (2*4*2*64*8)            // 8192
#define NB3     (2*2*2*64*8)            // 4096
#define NWF     (NB1 + NB2 + NB3)
#define NXP     (BATCH*C_INF*H_IN*W_IN) // 1048576 packed x elements
#define WOFF    (NPOS * F_OUT)          // out3 floats

typedef float  v4f    __attribute__((ext_vector_type(4)));
typedef short  short8 __attribute__((ext_vector_type(8)));
typedef __bf16 v8bf   __attribute__((ext_vector_type(8)));
typedef int    v4i    __attribute__((ext_vector_type(4)));
typedef uint   u32x4  __attribute__((ext_vector_type(4)));
typedef u32x4  u32x4_a4 __attribute__((aligned(4)));   // 16B load, 4B-aligned ok

__device__ inline short f2bf_hi(float x) {
    __hip_bfloat16 h = __float2bfloat16(x);      // RNE
    return __builtin_bit_cast(short, h);
}
__device__ inline float bf2f(short s) {
    __hip_bfloat16 h = __builtin_bit_cast(__hip_bfloat16, s);
    return __bfloat162float(h);
}
__device__ inline uint hipair(uint a, uint b) { return __builtin_amdgcn_perm(b, a, 0x07060302u); }
__device__ inline uint lopair(uint a, uint b) { return __builtin_amdgcn_perm(b, a, 0x05040100u); }

// slot -> k bijection for layer 1 (contiguous kj in the low 9 k-steps)
__device__ inline int slot_to_k1(int s, int qb, int e) {
    if (s < 9) {
        int pair = s*4 + qb;            // (c,ki) in [0,36)
        int c = pair/9, ki = pair - c*9;
        return c*81 + ki*9 + e;         // kj = e in [0,8)
    }
    int r = (s-9)*32 + qb*8 + e;        // remainder: kj = 8
    if (r >= 36) return -1;
    int c = r/9, ki = r - c*9;
    return c*81 + ki*9 + 8;
}

// ---------------- prep: pack x (hi,lo) + weights into b-frag images ----------------
__global__ __launch_bounds__(256)
void prep_kernel(const float* __restrict__ x,
                 const float* __restrict__ W1, const float* __restrict__ W2,
                 const float* __restrict__ W3,
                 uint* __restrict__ xp, short* __restrict__ wf)
{
    int i = blockIdx.x * 256 + threadIdx.x;
    if (i < NXP) {
        float v = x[i];
        short hi = f2bf_hi(v);
        short lo = f2bf_hi(v - bf2f(hi));
        xp[i] = ((uint)(ushort)hi << 16) | (uint)(ushort)lo;
        return;
    }
    i -= NXP;
    if (i >= NWF) return;
    float val;
    int p;
    if (i < NB1) {
        int t = i;
        int e = t & 7, lane = (t >> 3) & 63; p = (t >> 9) & 1;
        int rest = t >> 10;                  // s*4 + u
        int u = rest & 3, s = rest >> 2;
        int k = slot_to_k1(s, lane >> 4, e);
        int n = u*16 + (lane & 15);
        val = (k >= 0 && n < HID) ? W1[k*HID + n] : 0.f;
    } else if (i < NB1 + NB2) {
        int t = i - NB1;
        int e = t & 7, lane = (t >> 3) & 63; p = (t >> 9) & 1;
        int rest = t >> 10;
        int u = rest & 3, s = rest >> 2;
        int k = s*32 + ((lane >> 4) << 3) + e;   // linear (LDS h layout)
        int n = u*16 + (lane & 15);
        val = (k < HID && n < HID) ? W2[k*HID + n] : 0.f;
    } else {
        int t = i - NB1 - NB2;
        int e = t & 7, lane = (t >> 3) & 63; p = (t >> 9) & 1;
        int rest = t >> 10;
        int u = rest & 1, s = rest >> 1;
        int k = s*32 + ((lane >> 4) << 3) + e;
        int n = u*16 + (lane & 15);
        val = (k < HID && n < F_OUT) ? W3[k*F_OUT + n] : 0.f;
    }
    short hi = f2bf_hi(val);
    wf[i] = (p == 0) ? hi : f2bf_hi(val - bf2f(hi));
}

// ---------------- fused 3-layer MLP, wave-independent (ZERO block barriers) ----------------
// Each of the 4 waves owns M=32 rows (2 m-tiles) x all N. Inter-layer h (bf16-hi)
// lives in the wave's own LDS region; DS ops of one wave are FIFO -> no __syncthreads.
// out3: planar [F_OUT][NPOS] fp32, stored as dwordx4 in C-layout (64B runs).
__global__ __launch_bounds__(256, 4)
void mfma_mlp(const uint* __restrict__ xp,
              const float* __restrict__ b1, const float* __restrict__ b2,
              const float* __restrict__ b3,
              const short* __restrict__ wf, float* __restrict__ out3)
{
    __shared__ short h_hi[128 * 72];   // 18432 B; wave w owns rows [w*32, w*32+32)

    const int tid  = threadIdx.x;
    const int lane = tid & 63;
    const int w    = tid >> 6;
    const int q    = lane >> 4, col = lane & 15;
    const int mbase = blockIdx.x * MBLK;
    const int mw    = w * 32;          // this wave's row base within the block

    int xbase[2];
    #pragma unroll
    for (int t = 0; t < 2; ++t) {
        int pos = mbase + mw + t*16 + col;
        int b   = pos / (HO*WO); int rem = pos - b*(HO*WO);
        int y   = rem / WO;      int xc  = rem - y*WO;
        xbase[t] = b*(C_INF*H_IN*W_IN) + y*W_IN + xc;
    }

    const v4i* B1 = (const v4i*)wf;
    const v4i* B2 = (const v4i*)(wf + NB1);
    const v4i* B3 = (const v4i*)(wf + NB1 + NB2);

    // ---------------- layer 1: K=324 (11 k-steps), N=64 ----------------
    v4f acc[2][4];
    #pragma unroll
    for (int t = 0; t < 2; ++t)
        #pragma unroll
        for (int u = 0; u < 4; ++u)
            acc[t][u] = (v4f){0.f, 0.f, 0.f, 0.f};

    // 9 octet steps: this quad's 8 k's are 8 consecutive xp words (kj = 0..7)
    #pragma unroll 3
    for (int s = 0; s < 9; ++s) {
        const int pair = s*4 + q;
        const int c = pair/9, ki = pair - c*9;
        const int off = c*(H_IN*W_IN) + ki*W_IN;

        // b-frags first (long-latency hits overlap the a-frag perm work)
        v4i bhv[4], blv[4];
        #pragma unroll
        for (int u = 0; u < 4; ++u) {
            int fb = ((s*4 + u)*2)*64 + lane;
            bhv[u] = B1[fb];
            blv[u] = B1[fb + 64];
        }

        u32x4 wa[2], wb[2];
        #pragma unroll
        for (int t = 0; t < 2; ++t) {
            const uint* p = &xp[xbase[t] + off];
            wa[t] = *(const u32x4_a4*)(p);       // kj 0..3
            wb[t] = *(const u32x4_a4*)(p + 4);   // kj 4..7
        }
        short8 ah[2], al[2];
        #pragma unroll
        for (int t = 0; t < 2; ++t) {
            u32x4 hh, ll;
            hh.x = hipair(wa[t].x, wa[t].y); hh.y = hipair(wa[t].z, wa[t].w);
            hh.z = hipair(wb[t].x, wb[t].y); hh.w = hipair(wb[t].z, wb[t].w);
            ll.x = lopair(wa[t].x, wa[t].y); ll.y = lopair(wa[t].z, wa[t].w);
            ll.z = lopair(wb[t].x, wb[t].y); ll.w = lopair(wb[t].z, wb[t].w);
            ah[t] = __builtin_bit_cast(short8, hh);
            al[t] = __builtin_bit_cast(short8, ll);
        }
        #pragma unroll
        for (int u = 0; u < 4; ++u) {
            v8bf bh = __builtin_bit_cast(v8bf, bhv[u]);
            v8bf bl = __builtin_bit_cast(v8bf, blv[u]);
            #pragma unroll
            for (int t = 0; t < 2; ++t) {
                v8bf a_h = __builtin_bit_cast(v8bf, ah[t]);
                v8bf a_l = __builtin_bit_cast(v8bf, al[t]);
                acc[t][u] = __builtin_amdgcn_mfma_f32_16x16x32_bf16(a_h, bh, acc[t][u], 0, 0, 0);
                acc[t][u] = __builtin_amdgcn_mfma_f32_16x16x32_bf16(a_l, bh, acc[t][u], 0, 0, 0);
                acc[t][u] = __builtin_amdgcn_mfma_f32_16x16x32_bf16(a_h, bl, acc[t][u], 0, 0, 0);
            }
        }
    }
    // 2 remainder steps (kj = 8)
    #pragma unroll
    for (int sr = 0; sr < 2; ++sr) {
        const int s = 9 + sr;
        short8 ah[2], al[2];
        #pragma unroll
        for (int e = 0; e < 8; ++e) {
            int r = sr*32 + q*8 + e;
            bool valid = (r < 36);
            int c = valid ? r/9 : 0;
            int ki = r - c*9;
            int off = c*(H_IN*W_IN) + ki*W_IN + 8;
            #pragma unroll
            for (int t = 0; t < 2; ++t) {
                uint wv = valid ? xp[xbase[t] + off] : 0u;
                ah[t][e] = (short)(wv >> 16);
                al[t][e] = (short)(wv & 0xffffu);
            }
        }
        #pragma unroll
        for (int u = 0; u < 4; ++u) {
            int fb = ((s*4 + u)*2)*64 + lane;
            v8bf bh = __builtin_bit_cast(v8bf, B1[fb]);
            v8bf bl = __builtin_bit_cast(v8bf, B1[fb + 64]);
            #pragma unroll
            for (int t = 0; t < 2; ++t) {
                v8bf a_h = __builtin_bit_cast(v8bf, ah[t]);
                v8bf a_l = __builtin_bit_cast(v8bf, al[t]);
                acc[t][u] = __builtin_amdgcn_mfma_f32_16x16x32_bf16(a_h, bh, acc[t][u], 0, 0, 0);
                acc[t][u] = __builtin_amdgcn_mfma_f32_16x16x32_bf16(a_l, bh, acc[t][u], 0, 0, 0);
                acc[t][u] = __builtin_amdgcn_mfma_f32_16x16x32_bf16(a_h, bl, acc[t][u], 0, 0, 0);
            }
        }
    }

    // epilogue L1: + b1, relu, bf16-hi into this wave's LDS rows (no barrier needed)
    #pragma unroll
    for (int u = 0; u < 4; ++u) {
        int j = u*16 + col;
        float bias = (j < HID) ? b1[j] : 0.f;
        #pragma unroll
        for (int t = 0; t < 2; ++t) {
            #pragma unroll
            for (int r = 0; r < 4; ++r) {
                float v = fmaxf(acc[t][u][r] + bias, 0.f);
                int m = mw + t*16 + q*4 + r;
                h_hi[m*72 + j] = f2bf_hi(v);
            }
        }
    }

    // ---------------- layer 2: K=50 (2 k-steps), N=64, a=hi only ----------------
    v4f acc2[2][4];
    #pragma unroll
    for (int t = 0; t < 2; ++t)
        #pragma unroll
        for (int u = 0; u < 4; ++u)
            acc2[t][u] = (v4f){0.f, 0.f, 0.f, 0.f};

    #pragma unroll
    for (int s = 0; s < 2; ++s) {
        short8 ah2[2];
        #pragma unroll
        for (int t = 0; t < 2; ++t) {
            int m = mw + t*16 + col;
            ah2[t] = *(const short8*)&h_hi[m*72 + s*32 + q*8];
        }
        #pragma unroll
        for (int u = 0; u < 4; ++u) {
            int fb = ((s*4 + u)*2)*64 + lane;
            v8bf bh = __builtin_bit_cast(v8bf, B2[fb]);
            v8bf bl = __builtin_bit_cast(v8bf, B2[fb + 64]);
            #pragma unroll
            for (int t = 0; t < 2; ++t) {
                v8bf a_h = __builtin_bit_cast(v8bf, ah2[t]);
                acc2[t][u] = __builtin_amdgcn_mfma_f32_16x16x32_bf16(a_h, bh, acc2[t][u], 0, 0, 0);
                acc2[t][u] = __builtin_amdgcn_mfma_f32_16x16x32_bf16(a_h, bl, acc2[t][u], 0, 0, 0);
            }
        }
    }

    // epilogue L2 (wave has consumed all its h reads above; within-wave DS is FIFO)
    #pragma unroll
    for (int u = 0; u < 4; ++u) {
        int j = u*16 + col;
        float bias = (j < HID) ? b2[j] : 0.f;
        #pragma unroll
        for (int t = 0; t < 2; ++t) {
            #pragma unroll
            for (int r = 0; r < 4; ++r) {
                float v = fmaxf(acc2[t][u][r] + bias, 0.f);
                int m = mw + t*16 + q*4 + r;
                h_hi[m*72 + j] = f2bf_hi(v);
            }
        }
    }

    // ---------------- layer 3: K=50 (2 k-steps), N=18 (pad 32), a=hi only ----------------
    v4f acc3[2][2];
    #pragma unroll
    for (int t = 0; t < 2; ++t)
        #pragma unroll
        for (int u = 0; u < 2; ++u)
            acc3[t][u] = (v4f){0.f, 0.f, 0.f, 0.f};

    #pragma unroll
    for (int s = 0; s < 2; ++s) {
        short8 ah3[2];
        #pragma unroll
        for (int t = 0; t < 2; ++t) {
            int m = mw + t*16 + col;
            ah3[t] = *(const short8*)&h_hi[m*72 + s*32 + q*8];
        }
        #pragma unroll
        for (int u = 0; u < 2; ++u) {
            int fb = ((s*2 + u)*2)*64 + lane;
            v8bf bh = __builtin_bit_cast(v8bf, B3[fb]);
            v8bf bl = __builtin_bit_cast(v8bf, B3[fb + 64]);
            #pragma unroll
            for (int t = 0; t < 2; ++t) {
                v8bf a_h = __builtin_bit_cast(v8bf, ah3[t]);
                acc3[t][u] = __builtin_amdgcn_mfma_f32_16x16x32_bf16(a_h, bh, acc3[t][u], 0, 0, 0);
                acc3[t][u] = __builtin_amdgcn_mfma_f32_16x16x32_bf16(a_h, bl, acc3[t][u], 0, 0, 0);
            }
        }
    }

    // epilogue: + b3, direct planar dwordx4 stores (rows q*4..q*4+3 contiguous)
    #pragma unroll
    for (int u = 0; u < 2; ++u) {
        int j = u*16 + col;
        if (j < F_OUT) {
            float bias = b3[j];
            #pragma unroll
            for (int t = 0; t < 2; ++t) {
                v4f vs;
                #pragma unroll
                for (int r = 0; r < 4; ++r) vs[r] = acc3[t][u][r] + bias;
                *(v4f*)&out3[j*NPOS + mbase + mw + t*16 + q*4] = vs;
            }
        }
    }
}

// ---------------- fold (overlap-add) + divide, planar coalesced reads ----------------
__global__ __launch_bounds__(256)
void fold_kernel(const float* __restrict__ out3, float* __restrict__ out)
{
    const int idx = blockIdx.x * 256 + threadIdx.x;
    const int total = BATCH * 2 * OH * OW;
    if (idx >= total) return;

    int t = idx;
    const int ox = t % OW; t /= OW;
    const int oy = t % OH; t /= OH;
    const int c  = t & 1;  t >>= 1;
    const int b  = t;

    const int ylo = max(0, oy - 2), yhi = min(HO - 1, oy);
    const int xlo = max(0, ox - 2), xhi = min(WO - 1, ox);

    float s = 0.f;
    for (int y = ylo; y <= yhi; ++y) {
        const int ki = oy - y;
        for (int xx = xlo; xx <= xhi; ++xx) {
            const int kj = ox - xx;
            const int o  = (c*3 + ki)*3 + kj;
            s += out3[o*NPOS + (b*HO + y)*WO + xx];
        }
    }
    const float div = (float)((yhi - ylo + 1) * (xhi - xlo + 1));
    out[idx] = s / div;
}

// ---------------- launch ----------------
extern "C" void kernel_launch(void* const* d_in, const int* in_sizes, int n_in,
                              void* d_out, int out_size, void* d_ws, size_t ws_size,
                              hipStream_t stream)
{
    const float* x  = (const float*)d_in[0];
    const float* W1 = (const float*)d_in[1];
    const float* b1 = (const float*)d_in[2];
    const float* W2 = (const float*)d_in[3];
    const float* b2 = (const float*)d_in[4];
    const float* W3 = (const float*)d_in[5];
    const float* b3 = (const float*)d_in[6];

    float* out3 = (float*)d_ws;                               // 16.59 MB
    short* wf   = (short*)(out3 + WOFF);                      // 112 KB
    uint*  xp   = (uint*)(wf + NWF);                          // 4 MB

    const int nprep = (NXP + NWF + 255) / 256;
    prep_kernel<<<nprep, 256, 0, stream>>>(x, W1, W2, W3, xp, wf);

    mfma_mlp<<<NBLKS, 256, 0, stream>>>(xp, b1, b2, b3, wf, out3);

    const int total = BATCH * 2 * OH * OW;
    fold_kernel<<<(total + 255) / 256, 256, 0, stream>>>(out3, (float*)d_out);
}